// Round 9
// baseline (623.129 us; speedup 1.0000x reference)
//
#include <hip/hip_runtime.h>
#include <cstdint>
#include <cstddef>

typedef _Float16 f16;
typedef _Float16 f16x8 __attribute__((ext_vector_type(8)));
typedef float f32x4 __attribute__((ext_vector_type(4)));

// Raw workgroup barrier WITHOUT __syncthreads() full-drain semantics:
// drain lgkmcnt only (LDS visibility both directions); global loads stay
// in flight across the barrier, waited by counted vmcnt at first use.
#define BAR_LDS() asm volatile("s_waitcnt lgkmcnt(0)\n\ts_barrier" ::: "memory")

// ---------------------------------------------------------------------------
// W fragment-tiled for mfma_f32_16x16x32_f16 B operand:
// lane l holds B[n = nf*16 + (l&15)][k = kb*32 + (l>>4)*8 + j]; element
// (n,k) at flat idx ((n>>4)*(K/32) + (k>>5))*512 + (((k>>3)&3)*16+(n&15))*8
// + (k&7). One fragment = one coalesced global_load_dwordx4 per wave.
// ---------------------------------------------------------------------------
template <int I, int O>
__global__ void prep_coef(const float* __restrict__ coef,
                          const float* __restrict__ ssp,
                          f16* __restrict__ Wt) {
  constexpr int K32 = (9 * I) / 32;
  int tid = blockIdx.x * 256 + threadIdx.x;
  if (tid >= I * O) return;
  int i = tid / O, o = tid % O;             // o fastest -> coalesced coef reads
  float s = ssp[tid];
  const float* c = coef + (size_t)tid * 8;
  f16x8 out;
#pragma unroll
  for (int g = 0; g < 8; ++g) out[g] = (f16)(c[g] * s);
  size_t addr = ((size_t)(o >> 4) * K32 + (i >> 2)) * 512 +
                (size_t)(((i & 3) * 16) + (o & 15)) * 8;
  *(f16x8*)(Wt + addr) = out;
}

template <int I, int O>
__global__ void prep_base(const float* __restrict__ sb, f16* __restrict__ Wt) {
  constexpr int K32 = (9 * I) / 32;
  int tid = blockIdx.x * 256 + threadIdx.x;
  if (tid >= (I / 8) * O) return;
  int i8 = tid / O, o = tid % O;            // o fastest -> coalesced writes
  f16x8 out;
#pragma unroll
  for (int s = 0; s < 8; ++s)
    out[s] = (f16)sb[(size_t)(i8 * 8 + s) * O + o];
  size_t addr = ((size_t)(o >> 4) * K32 + (I / 4) + (i8 >> 2)) * 512 +
                (size_t)(((i8 & 3) * 16) + (o & 15)) * 8;
  *(f16x8*)(Wt + addr) = out;
}

// ---------------------------------------------------------------------------
// 8-slot cubic B-spline basis, packed-shift form (verified R6, absmax 0.0625).
// ---------------------------------------------------------------------------
__device__ __forceinline__ f16x8 spline8(float h) {
  float v = __builtin_fmaf(2.5f, h, 5.5f);
  float c = floorf(v);
  float f = v - c;
  float f2 = f * f, f3 = f2 * f;
  float b3 = f3 * (1.f / 6.f);
  float t = 1.f - f;
  float b0 = t * t * t * (1.f / 6.f);
  float b1 = (2.f / 3.f) - f2 + 0.5f * f3;
  float b2 = 1.f - b0 - b1 - b3;
  unsigned int u01 =
      __builtin_bit_cast(unsigned int, __builtin_amdgcn_cvt_pkrtz(b0, b1));
  unsigned int u23 =
      __builtin_bit_cast(unsigned int, __builtin_amdgcn_cvt_pkrtz(b2, b3));
  unsigned long long pk = (unsigned long long)u01 |
                          ((unsigned long long)u23 << 32);
  int ci = (int)c;
  int s = (ci - 3) * 16;                // bit offset of slot c-3
  __uint128_t r = 0;
  if (s >= 0) {
    if (s < 128) r = (__uint128_t)pk << s;
  } else {
    int q = -s;
    if (q < 64) r = (__uint128_t)(pk >> q);
  }
  return __builtin_bit_cast(f16x8, r);
}

// ---------------------------------------------------------------------------
// Fused KAN GEMM, 128(M) x 256(N) tile, BK=64. R15: SAME WORK, 2x WAVES.
//
// R7-R14 established: latency-bound at 2 waves/SIMD (MfmaUtil pinned
// 28-32%; MFMA 35% + pure VALU 8% of wall, HBM 24%, L2 ~33%, conflicts 0).
// R9 failed because smaller blocks scaled gen/B work with the waves; R14
// failed because wave-private gen duplicated VALU. R15 keeps the R11 block
// (tile, LDS, gen layout, barriers, B pipeline) and ONLY splits it across
// 512 threads / 8 waves: wave tile 64x128 -> 64x64 (acc 128 -> 64 AGPR),
// gen 2 rows/thread instead of 4. Per-CU committed work identical to R11;
// waves/SIMD 2 -> 4 (16 waves/CU). __launch_bounds__(512,4) forces the
// 128-reg/wave fit (acc 64 + av 16 + bvA/bvB 32 + misc).
//
// Kept: XCD pinning (8 (x,z) pairs == wgid%8 == XCD; W slice 2.36 MB/XCD
// L2-resident; strided split-K), lgkm-only barrier (R11), B register
// pipeline, setprio on MFMA clusters, atomicAdd split-K epilogue.
// Arithmetic bit-identical to R6-R14 (absmax 0.0625).
// ---------------------------------------------------------------------------
template <int I, int ATOMIC, int NX, int NZ>
__global__ __launch_bounds__(512, 4) void gemm_kan(const float* __restrict__ H,
                                                   const f16* __restrict__ W,
                                                   float* __restrict__ C,
                                                   int N) {
  constexpr int K = 9 * I;
  constexpr int KB = 8 * I;                   // spline/base boundary (mult 64)
  constexpr int K32 = K / 32;
  constexpr int KSTEP = 64 * NZ;              // strided split-K step
  constexpr int NSTEP = K / KSTEP;
  __shared__ __align__(16) f16 sA[2 * 128 * 64];  // 32 KB double-buffered
  const int t = threadIdx.x;
  const int wg = blockIdx.x;
  const int pr = wg & 7;                      // XCD-pair id (wgid%8 == XCD)
  const int n0 = (pr % NX) * 256;
  const int m0 = (wg >> 3) * 128;
  const int kBeg = (pr / NX) * 64;
  const int w = t >> 6, lane = t & 63;
  const int wm = (w >> 2) * 64, wn = (w & 3) * 64;  // 2x4 waves of 64x64
  const int lr = lane & 15, lq = lane >> 4;
  const int srow = t >> 3;                    // staging row 0..63 (q adds 64)
  const int j_ = t & 7;                       // chunk col 0..7
  const int js = j_ ^ (srow & 7);             // swizzled chunk col

  f32x4 acc[4][4] = {};
  const float* Hrow = H + (size_t)(m0 + srow) * I;

  float hs[2];

  // Generate the 128x64 A-tile for k-range [kg, kg+64) into buffer wb.
  // 512 threads: 2 rows/thread (q*64 + srow). Same layout/swizzle as R11.
  auto genTile = [&](int kg, f16* wb) {
    if (kg < KB) {
#pragma unroll
      for (int q = 0; q < 2; ++q)
        *(f16x8*)&wb[((q * 64 + srow) * 8 + js) * 8] = spline8(hs[q]);
      const int kn = kg + KSTEP;
      if (kn < KB) {
        const int i0n = kn >> 3;
#pragma unroll
        for (int q = 0; q < 2; ++q)
          hs[q] = Hrow[(size_t)(q * 64) * I + i0n + j_];
      }
    } else {
      const int c0 = (kg - KB) + j_ * 8;      // 8 consecutive silu inputs
#pragma unroll
      for (int q = 0; q < 2; ++q) {           // per-q to cap transient regs
        const f32x4* p = (const f32x4*)(Hrow + (size_t)(q * 64) * I + c0);
        f32x4 a0 = p[0], a1 = p[1];
        f16x8 o;
#pragma unroll
        for (int e = 0; e < 8; ++e) {
          float h = (e < 4) ? a0[e & 3] : a1[e & 3];
          o[e] = (f16)(h / (1.f + __expf(-h)));
        }
        *(f16x8*)&wb[((q * 64 + srow) * 8 + js) * 8] = o;
      }
    }
  };

  // prologue: prefetch H, preload first B half (kk=0), generate tile 0
  {
    const int i0 = kBeg >> 3;                 // kBeg <= 192 < KB always
#pragma unroll
    for (int q = 0; q < 2; ++q)
      hs[q] = Hrow[(size_t)(q * 64) * I + i0 + j_];
  }
  // wave's fragment-tiled W pointer at current k-step (advances by KSTEP)
  const f16* pk = W + ((size_t)((n0 + wn) >> 4) * K32 + (kBeg >> 5)) * 512 +
                  lane * 8;
  f16x8 bvA[4];
#pragma unroll
  for (int j = 0; j < 4; ++j)
    bvA[j] = *(const f16x8*)(pk + (size_t)j * K32 * 512);
  genTile(kBeg, sA);                          // also prefetches hs for next
  BAR_LDS();

  int cur = 0;
  for (int s = 0; s < NSTEP; ++s) {
    const f16* rb = sA + cur * (128 * 64);
    f16* wb = sA + (cur ^ 1) * (128 * 64);

    // B frags for kk=32 of THIS step: latency hides under av0 + MFMA half0.
    f16x8 bvB[4];
#pragma unroll
    for (int j = 0; j < 4; ++j)
      bvB[j] = *(const f16x8*)(pk + (size_t)j * K32 * 512 + 512);

    // av half 0 from LDS
    f16x8 av[4];
#pragma unroll
    for (int i = 0; i < 4; ++i) {
      const int ra = wm + i * 16 + lr;
      const int ca = lq ^ (ra & 7);
      av[i] = *(const f16x8*)&rb[ra * 64 + ca * 8];
    }

    __builtin_amdgcn_s_setprio(1);
#pragma unroll
    for (int i = 0; i < 4; ++i)
#pragma unroll
      for (int j = 0; j < 4; ++j)
        acc[i][j] = __builtin_amdgcn_mfma_f32_16x16x32_f16(av[i], bvA[j],
                                                           acc[i][j], 0, 0, 0);
    __builtin_amdgcn_s_setprio(0);

    // av half 1
#pragma unroll
    for (int i = 0; i < 4; ++i) {
      const int ra = wm + i * 16 + lr;
      const int ca = (4 + lq) ^ (ra & 7);
      av[i] = *(const f16x8*)&rb[ra * 64 + ca * 8];
    }

    // Generate NEXT tile into the other buffer (independent of MFMA).
    const bool more = (s + 1 < NSTEP);
    if (more) genTile(kBeg + (s + 1) * KSTEP, wb);

    // NEXT step's bv(kk=0): stays in flight across the raw barrier.
    pk += (size_t)(KSTEP / 32) * 512;
    if (more) {
#pragma unroll
      for (int j = 0; j < 4; ++j)
        bvA[j] = *(const f16x8*)(pk + (size_t)j * K32 * 512);
    }

    __builtin_amdgcn_s_setprio(1);
#pragma unroll
    for (int i = 0; i < 4; ++i)
#pragma unroll
      for (int j = 0; j < 4; ++j)
        acc[i][j] = __builtin_amdgcn_mfma_f32_16x16x32_f16(av[i], bvB[j],
                                                           acc[i][j], 0, 0, 0);
    __builtin_amdgcn_s_setprio(0);

    BAR_LDS();         // lgkm-only drain: wb visible, rb safely reusable
    cur ^= 1;
  }

#pragma unroll
  for (int i = 0; i < 4; ++i) {
#pragma unroll
    for (int j = 0; j < 4; ++j) {
      const int col = n0 + wn + j * 16 + lr;
#pragma unroll
      for (int r = 0; r < 4; ++r) {
        const int row = m0 + wm + i * 16 + lq * 4 + r;
        if (ATOMIC)
          atomicAdd(&C[(size_t)row * N + col], acc[i][j][r]);
        else
          C[(size_t)row * N + col] = acc[i][j][r];
      }
    }
  }
}

// ---------------------------------------------------------------------------
extern "C" void kernel_launch(void* const* d_in, const int* in_sizes, int n_in,
                              void* d_out, int out_size, void* d_ws,
                              size_t ws_size, hipStream_t stream) {
  const float* x     = (const float*)d_in[0];
  const float* coef1 = (const float*)d_in[1];
  const float* sb1   = (const float*)d_in[2];
  const float* ssp1  = (const float*)d_in[3];
  const float* coef2 = (const float*)d_in[4];
  const float* sb2   = (const float*)d_in[5];
  const float* ssp2  = (const float*)d_in[6];

  const int Mtot = 8192;
  const int I1 = 512, O1 = 2048, K1 = I1 * 9;   // 4608
  const int I2 = 2048, O2 = 512, K2 = I2 * 9;   // 18432

  char* ws = (char*)d_ws;
  const size_t szW1 = (size_t)O1 * K1 * sizeof(f16);     // 18.9 MB
  const size_t szW2 = (size_t)O2 * K2 * sizeof(f16);     // 18.9 MB
  const size_t szH  = (size_t)Mtot * O1 * sizeof(float); // 67.1 MB
  if (ws_size < szW1 + szW2 + szH) return;  // cannot run; fail visibly
  f16*   W1 = (f16*)ws;
  f16*   W2 = (f16*)(ws + szW1);
  float* h1 = (float*)(ws + szW1 + szW2);

  // weight prep (fragment-tiled layout, 16x16x32 B-operand tiles)
  {
    int n1 = I1 * O1;
    prep_coef<512, 2048><<<(n1 + 255) / 256, 256, 0, stream>>>(coef1, ssp1, W1);
    prep_base<512, 2048><<<(n1 / 8 + 255) / 256, 256, 0, stream>>>(sb1, W1);
    int n2 = I2 * O2;
    prep_coef<2048, 512><<<(n2 + 255) / 256, 256, 0, stream>>>(coef2, ssp2, W2);
    prep_base<2048, 512><<<(n2 / 8 + 255) / 256, 256, 0, stream>>>(sb2, W2);
  }

  // layer 1: h1 = KanAct(x) @ W1^T — 512 blocks x 512 threads, 2 blk/CU.
  gemm_kan<512, 0, 8, 1><<<dim3(512), 512, 0, stream>>>(x, W1, h1, O1);

  // layer 2: out = KanAct(h1) @ W2^T — strided split-K=4, pair=(x,z).
  (void)hipMemsetAsync(d_out, 0, (size_t)Mtot * O2 * sizeof(float), stream);
  gemm_kan<2048, 1, 2, 4><<<dim3(512), 512, 0, stream>>>(h1, W2,
                                                         (float*)d_out, O2);
}

// Round 10
// 567.382 us; speedup vs baseline: 1.0983x; 1.0983x over previous
//
#include <hip/hip_runtime.h>
#include <cstdint>
#include <cstddef>

typedef _Float16 f16;
typedef _Float16 f16x8 __attribute__((ext_vector_type(8)));
typedef float f32x4 __attribute__((ext_vector_type(4)));

// Raw workgroup barrier WITHOUT __syncthreads() full-drain semantics:
// drain lgkmcnt only (LDS visibility both directions); global loads stay
// in flight across the barrier, waited by counted vmcnt at first use.
#define BAR_LDS() asm volatile("s_waitcnt lgkmcnt(0)\n\ts_barrier" ::: "memory")

// ---------------------------------------------------------------------------
// W fragment-tiled for mfma_f32_16x16x32_f16 B operand:
// lane l holds B[n = nf*16 + (l&15)][k = kb*32 + (l>>4)*8 + j]; element
// (n,k) at flat idx ((n>>4)*(K/32) + (k>>5))*512 + (((k>>3)&3)*16+(n&15))*8
// + (k&7). One fragment = one coalesced global_load_dwordx4 per wave.
// ---------------------------------------------------------------------------
template <int I, int O>
__global__ void prep_coef(const float* __restrict__ coef,
                          const float* __restrict__ ssp,
                          f16* __restrict__ Wt) {
  constexpr int K32 = (9 * I) / 32;
  int tid = blockIdx.x * 256 + threadIdx.x;
  if (tid >= I * O) return;
  int i = tid / O, o = tid % O;             // o fastest -> coalesced coef reads
  float s = ssp[tid];
  const float* c = coef + (size_t)tid * 8;
  f16x8 out;
#pragma unroll
  for (int g = 0; g < 8; ++g) out[g] = (f16)(c[g] * s);
  size_t addr = ((size_t)(o >> 4) * K32 + (i >> 2)) * 512 +
                (size_t)(((i & 3) * 16) + (o & 15)) * 8;
  *(f16x8*)(Wt + addr) = out;
}

template <int I, int O>
__global__ void prep_base(const float* __restrict__ sb, f16* __restrict__ Wt) {
  constexpr int K32 = (9 * I) / 32;
  int tid = blockIdx.x * 256 + threadIdx.x;
  if (tid >= (I / 8) * O) return;
  int i8 = tid / O, o = tid % O;            // o fastest -> coalesced writes
  f16x8 out;
#pragma unroll
  for (int s = 0; s < 8; ++s)
    out[s] = (f16)sb[(size_t)(i8 * 8 + s) * O + o];
  size_t addr = ((size_t)(o >> 4) * K32 + (I / 4) + (i8 >> 2)) * 512 +
                (size_t)(((i8 & 3) * 16) + (o & 15)) * 8;
  *(f16x8*)(Wt + addr) = out;
}

// ---------------------------------------------------------------------------
// 8-slot cubic B-spline basis, packed-shift form (verified R6, absmax 0.0625).
// ---------------------------------------------------------------------------
__device__ __forceinline__ f16x8 spline8(float h) {
  float v = __builtin_fmaf(2.5f, h, 5.5f);
  float c = floorf(v);
  float f = v - c;
  float f2 = f * f, f3 = f2 * f;
  float b3 = f3 * (1.f / 6.f);
  float t = 1.f - f;
  float b0 = t * t * t * (1.f / 6.f);
  float b1 = (2.f / 3.f) - f2 + 0.5f * f3;
  float b2 = 1.f - b0 - b1 - b3;
  unsigned int u01 =
      __builtin_bit_cast(unsigned int, __builtin_amdgcn_cvt_pkrtz(b0, b1));
  unsigned int u23 =
      __builtin_bit_cast(unsigned int, __builtin_amdgcn_cvt_pkrtz(b2, b3));
  unsigned long long pk = (unsigned long long)u01 |
                          ((unsigned long long)u23 << 32);
  int ci = (int)c;
  int s = (ci - 3) * 16;                // bit offset of slot c-3
  __uint128_t r = 0;
  if (s >= 0) {
    if (s < 128) r = (__uint128_t)pk << s;
  } else {
    int q = -s;
    if (q < 64) r = (__uint128_t)(pk >> q);
  }
  return __builtin_bit_cast(f16x8, r);
}

// ---------------------------------------------------------------------------
// Fused KAN GEMM, 128(M) x 256(N) tile, BK=64. R16: R15's 8-wave block with
// a REGISTER DIET (R15 spilled: WRITE_SIZE 65->224 MB at the 128-reg bound,
// confounding the 4-waves/SIMD test; occupancy doubled but MfmaUtil fell).
//
// R11 model: per SIMD per step the pipe times ADD (MFMA 2483 + L2/B ~2290 +
// LDS ~1150 + VALU ~600 ~= wall 7067) -- 2 waves/SIMD give no overlap. R16
// keeps per-CU work identical to R11 and runs 16 waves/CU (4/SIMD) with
// <=128 regs/wave:
//   - acc 64 AGPR (64x64 wave tile, 2x4 wave grid over 128x256 block)
//   - av half0 read INLINE per-i in the MFMA cluster (live 8 regs, not 16)
//   - bvB issued AFTER the MFMA-half0 cluster: MFMA is async to the wave's
//     stream, so half0's ~310-cyc pipe execution hides bvB's L2 latency;
//     bvB live range = half-step -> genTile-phase reg peak drops (the R15
//     spill point). MFMA half1's bvB wait = counted vmcnt (bvA-next + H
//     issued after it).
//   - av half1 pre-read BEFORE genTile (else its lgkm wait FIFO-blocks
//     behind gen's ds_writes).
// Kept: XCD pinning (8 (x,z) pairs == wgid%8 == XCD; W slice 2.36 MB/XCD),
// strided split-K, lgkm-only barrier, setprio, atomicAdd split-K epilogue.
// Arithmetic bit-identical to R6-R15 (absmax 0.0625).
// ---------------------------------------------------------------------------
template <int I, int ATOMIC, int NX, int NZ>
__global__ __launch_bounds__(512, 4) void gemm_kan(const float* __restrict__ H,
                                                   const f16* __restrict__ W,
                                                   float* __restrict__ C,
                                                   int N) {
  constexpr int K = 9 * I;
  constexpr int KB = 8 * I;                   // spline/base boundary (mult 64)
  constexpr int K32 = K / 32;
  constexpr int KSTEP = 64 * NZ;              // strided split-K step
  constexpr int NSTEP = K / KSTEP;
  __shared__ __align__(16) f16 sA[2 * 128 * 64];  // 32 KB double-buffered
  const int t = threadIdx.x;
  const int wg = blockIdx.x;
  const int pr = wg & 7;                      // XCD-pair id (wgid%8 == XCD)
  const int n0 = (pr % NX) * 256;
  const int m0 = (wg >> 3) * 128;
  const int kBeg = (pr / NX) * 64;
  const int w = t >> 6, lane = t & 63;
  const int wm = (w >> 2) * 64, wn = (w & 3) * 64;  // 2x4 waves of 64x64
  const int lr = lane & 15, lq = lane >> 4;
  const int srow = t >> 3;                    // staging row 0..63 (q adds 64)
  const int j_ = t & 7;                       // chunk col 0..7
  const int js = j_ ^ (srow & 7);             // swizzled chunk col

  f32x4 acc[4][4] = {};
  const float* Hrow = H + (size_t)(m0 + srow) * I;

  float hs[2];

  // Generate the 128x64 A-tile for k-range [kg, kg+64) into buffer wb.
  // 512 threads: 2 rows/thread (q*64 + srow). Same layout/swizzle as R11.
  auto genTile = [&](int kg, f16* wb) {
    if (kg < KB) {
#pragma unroll
      for (int q = 0; q < 2; ++q)
        *(f16x8*)&wb[((q * 64 + srow) * 8 + js) * 8] = spline8(hs[q]);
      const int kn = kg + KSTEP;
      if (kn < KB) {
        const int i0n = kn >> 3;
#pragma unroll
        for (int q = 0; q < 2; ++q)
          hs[q] = Hrow[(size_t)(q * 64) * I + i0n + j_];
      }
    } else {
      const int c0 = (kg - KB) + j_ * 8;      // 8 consecutive silu inputs
#pragma unroll
      for (int q = 0; q < 2; ++q) {           // per-q to cap transient regs
        const f32x4* p = (const f32x4*)(Hrow + (size_t)(q * 64) * I + c0);
        f32x4 a0 = p[0], a1 = p[1];
        f16x8 o;
#pragma unroll
        for (int e = 0; e < 8; ++e) {
          float h = (e < 4) ? a0[e & 3] : a1[e & 3];
          o[e] = (f16)(h / (1.f + __expf(-h)));
        }
        *(f16x8*)&wb[((q * 64 + srow) * 8 + js) * 8] = o;
      }
    }
  };

  // prologue: prefetch H, preload first B half (kk=0), generate tile 0
  {
    const int i0 = kBeg >> 3;                 // kBeg <= 192 < KB always
#pragma unroll
    for (int q = 0; q < 2; ++q)
      hs[q] = Hrow[(size_t)(q * 64) * I + i0 + j_];
  }
  // wave's fragment-tiled W pointer at current k-step (advances by KSTEP)
  const f16* pk = W + ((size_t)((n0 + wn) >> 4) * K32 + (kBeg >> 5)) * 512 +
                  lane * 8;
  f16x8 bvA[4];
#pragma unroll
  for (int j = 0; j < 4; ++j)
    bvA[j] = *(const f16x8*)(pk + (size_t)j * K32 * 512);
  genTile(kBeg, sA);                          // also prefetches hs for next
  BAR_LDS();

  int cur = 0;
  for (int s = 0; s < NSTEP; ++s) {
    const f16* rb = sA + cur * (128 * 64);
    f16* wb = sA + (cur ^ 1) * (128 * 64);

    // MFMA half0: av read inline per-i (8 live regs), bvA from last step.
    __builtin_amdgcn_s_setprio(1);
#pragma unroll
    for (int i = 0; i < 4; ++i) {
      const int ra = wm + i * 16 + lr;
      const int ca = lq ^ (ra & 7);
      const f16x8 avi = *(const f16x8*)&rb[ra * 64 + ca * 8];
#pragma unroll
      for (int j = 0; j < 4; ++j)
        acc[i][j] = __builtin_amdgcn_mfma_f32_16x16x32_f16(avi, bvA[j],
                                                           acc[i][j], 0, 0, 0);
    }
    __builtin_amdgcn_s_setprio(0);

    // bvB issued AFTER half0's MFMAs: latency hides under their pipe
    // execution (MFMA async to wave stream). Live only until half1.
    f16x8 bvB[4];
#pragma unroll
    for (int j = 0; j < 4; ++j)
      bvB[j] = *(const f16x8*)(pk + (size_t)j * K32 * 512 + 512);

    // av half1 pre-read BEFORE genTile (avoid lgkm FIFO behind ds_writes).
    f16x8 av[4];
#pragma unroll
    for (int i = 0; i < 4; ++i) {
      const int ra = wm + i * 16 + lr;
      const int ca = (4 + lq) ^ (ra & 7);
      av[i] = *(const f16x8*)&rb[ra * 64 + ca * 8];
    }

    // Generate NEXT tile into the other buffer (independent of MFMA).
    const bool more = (s + 1 < NSTEP);
    if (more) genTile(kBeg + (s + 1) * KSTEP, wb);

    // NEXT step's bv(kk=0): stays in flight across the raw barrier.
    pk += (size_t)(KSTEP / 32) * 512;
    if (more) {
#pragma unroll
      for (int j = 0; j < 4; ++j)
        bvA[j] = *(const f16x8*)(pk + (size_t)j * K32 * 512);
    }

    __builtin_amdgcn_s_setprio(1);
#pragma unroll
    for (int i = 0; i < 4; ++i)
#pragma unroll
      for (int j = 0; j < 4; ++j)
        acc[i][j] = __builtin_amdgcn_mfma_f32_16x16x32_f16(av[i], bvB[j],
                                                           acc[i][j], 0, 0, 0);
    __builtin_amdgcn_s_setprio(0);

    BAR_LDS();         // lgkm-only drain: wb visible, rb safely reusable
    cur ^= 1;
  }

#pragma unroll
  for (int i = 0; i < 4; ++i) {
#pragma unroll
    for (int j = 0; j < 4; ++j) {
      const int col = n0 + wn + j * 16 + lr;
#pragma unroll
      for (int r = 0; r < 4; ++r) {
        const int row = m0 + wm + i * 16 + lq * 4 + r;
        if (ATOMIC)
          atomicAdd(&C[(size_t)row * N + col], acc[i][j][r]);
        else
          C[(size_t)row * N + col] = acc[i][j][r];
      }
    }
  }
}

// ---------------------------------------------------------------------------
extern "C" void kernel_launch(void* const* d_in, const int* in_sizes, int n_in,
                              void* d_out, int out_size, void* d_ws,
                              size_t ws_size, hipStream_t stream) {
  const float* x     = (const float*)d_in[0];
  const float* coef1 = (const float*)d_in[1];
  const float* sb1   = (const float*)d_in[2];
  const float* ssp1  = (const float*)d_in[3];
  const float* coef2 = (const float*)d_in[4];
  const float* sb2   = (const float*)d_in[5];
  const float* ssp2  = (const float*)d_in[6];

  const int Mtot = 8192;
  const int I1 = 512, O1 = 2048, K1 = I1 * 9;   // 4608
  const int I2 = 2048, O2 = 512, K2 = I2 * 9;   // 18432

  char* ws = (char*)d_ws;
  const size_t szW1 = (size_t)O1 * K1 * sizeof(f16);     // 18.9 MB
  const size_t szW2 = (size_t)O2 * K2 * sizeof(f16);     // 18.9 MB
  const size_t szH  = (size_t)Mtot * O1 * sizeof(float); // 67.1 MB
  if (ws_size < szW1 + szW2 + szH) return;  // cannot run; fail visibly
  f16*   W1 = (f16*)ws;
  f16*   W2 = (f16*)(ws + szW1);
  float* h1 = (float*)(ws + szW1 + szW2);

  // weight prep (fragment-tiled layout, 16x16x32 B-operand tiles)
  {
    int n1 = I1 * O1;
    prep_coef<512, 2048><<<(n1 + 255) / 256, 256, 0, stream>>>(coef1, ssp1, W1);
    prep_base<512, 2048><<<(n1 / 8 + 255) / 256, 256, 0, stream>>>(sb1, W1);
    int n2 = I2 * O2;
    prep_coef<2048, 512><<<(n2 + 255) / 256, 256, 0, stream>>>(coef2, ssp2, W2);
    prep_base<2048, 512><<<(n2 / 8 + 255) / 256, 256, 0, stream>>>(sb2, W2);
  }

  // layer 1: h1 = KanAct(x) @ W1^T — 512 blocks x 512 threads, 2 blk/CU.
  gemm_kan<512, 0, 8, 1><<<dim3(512), 512, 0, stream>>>(x, W1, h1, O1);

  // layer 2: out = KanAct(h1) @ W2^T — strided split-K=4, pair=(x,z).
  (void)hipMemsetAsync(d_out, 0, (size_t)Mtot * O2 * sizeof(float), stream);
  gemm_kan<2048, 1, 2, 4><<<dim3(512), 512, 0, stream>>>(h1, W2,
                                                         (float*)d_out, O2);
}